// Round 11
// baseline (130.952 us; speedup 1.0000x reference)
//
#include <hip/hip_runtime.h>

// GCN layer: h = segment_sum(x[src], dst); out = h @ W^T + b
// N=40000, E=640000, D=128. Harness compares at bf16 tolerance (0.4625).
// ~57us harness-fixed (256MiB ws poison fill + out/in restores) + ~17us HBM
// cold/eviction tax. r10 = 121.7us.
//
// r11: deep-MLP gather. Phase A pads each node's slot list to a multiple of
// 16 with dummy index 40000 (xb row 40000 = zeros) -> no masking in phase B;
// per node, ALL bursts' loads (up to 12 dwordx4) issue before any
// accumulation (guarded-unrolled, compile-time v[] indexing - no scratch).
//
//  K1 prep: [distribute: 313 blocks x 2048 edges -> LDS hist(1250), write
//     region cells (16-slot, block-local rank) + histg] + x->bf16 + W->bf16
//     + zero-row block
//  K2 gcn_main: 1250 blocks (32-node ranges): A) bin own 313 cells into LDS
//     slot[32][48] ushort + pad16; B) whole-node MLP gather (wave = 8 nodes);
//     C) mfma_f32_16x16x32_bf16, wave = (tile w&1, j-half w>>1).
//     C/D col=lane&15, row=quad*4+reg (verified r4-r10).

#define NN 40000
#define NE 640000
#define DIM 128
#define CAP 48
#define ZROW 40000        // dummy zero row index in xb

#define NR 1250           // 32-node dst ranges; 1250*32 == 40000 exactly
#define NPR 32
#define RC 16             // slots per (range, dist-block) cell
#define DIST_BLOCKS 313   // x 2048 edges = 641024 >= NE
#define CVX_BLOCKS 5000   // NN*DIM/4/256

typedef __attribute__((ext_vector_type(8))) short bf16x8;
typedef __attribute__((ext_vector_type(4))) float f32x4;

__device__ __forceinline__ unsigned short f2bf(float f) {
    unsigned u = __float_as_uint(f);
    unsigned r = u + 0x7FFFu + ((u >> 16) & 1u);  // RTNE
    return (unsigned short)(r >> 16);
}
__device__ __forceinline__ float bflo(unsigned u) { return __uint_as_float(u << 16); }
__device__ __forceinline__ float bfhi(unsigned u) { return __uint_as_float(u & 0xffff0000u); }

__global__ __launch_bounds__(256) void prep(const float* __restrict__ x,
                                            const float* __restrict__ W,
                                            const int* __restrict__ src,
                                            const int* __restrict__ dst,
                                            int* __restrict__ histg,
                                            unsigned int* __restrict__ region,
                                            unsigned short* __restrict__ xb,
                                            unsigned short* __restrict__ Wb) {
    __shared__ int hist[NR];
    int bid = blockIdx.x;
    int t = threadIdx.x;
    if (bid < DIST_BLOCKS) {
        for (int i = t; i < NR; i += 256) hist[i] = 0;
        __syncthreads();
        int e0 = bid * 2048;
        int dv[8], sv[8], rg8[8], rk8[8];
#pragma unroll
        for (int q = 0; q < 8; ++q) {
            int e = e0 + q * 256 + t;
            if (e < NE) { dv[q] = dst[e]; sv[q] = src[e]; } else dv[q] = -1;
        }
#pragma unroll
        for (int q = 0; q < 8; ++q) {
            if (dv[q] >= 0) { rg8[q] = dv[q] >> 5; rk8[q] = atomicAdd(&hist[rg8[q]], 1); }
        }
#pragma unroll
        for (int q = 0; q < 8; ++q) {
            if (dv[q] >= 0 && (unsigned)rk8[q] < (unsigned)RC) {
                region[(((size_t)rg8[q] * DIST_BLOCKS + bid) << 4) + rk8[q]] =
                    ((unsigned)sv[q] & 0xFFFFu) | (((unsigned)dv[q] & 31u) << 16);
            }
        }
        __syncthreads();  // hist final
        for (int i = t; i < NR; i += 256) histg[i * DIST_BLOCKS + bid] = hist[i];
    } else if (bid < DIST_BLOCKS + CVX_BLOCKS) {
        int i = ((bid - DIST_BLOCKS) * 256 + t) * 4;
        const float4 v = *(const float4*)(x + i);
        ushort4 o;
        o.x = f2bf(v.x); o.y = f2bf(v.y); o.z = f2bf(v.z); o.w = f2bf(v.w);
        *(ushort4*)(xb + i) = o;
    } else if (bid < DIST_BLOCKS + CVX_BLOCKS + 16) {
        int i = ((bid - DIST_BLOCKS - CVX_BLOCKS) * 256 + t) * 4;
        const float4 v = *(const float4*)(W + i);
        ushort4 o;
        o.x = f2bf(v.x); o.y = f2bf(v.y); o.z = f2bf(v.z); o.w = f2bf(v.w);
        *(ushort4*)(Wb + i) = o;
    } else {
        // zero dummy row (256 B)
        if (t < 64) ((unsigned int*)(xb + (size_t)ZROW * DIM))[t] = 0u;
    }
}

// hs: 2 tiles of 16 nodes, fgroup-major: tile T at hs + T*2176 (ushorts);
// fgroup f at +f*136, node k at +k*8 (16B units, conflict-free ds_read_b128).
#define FG_STRIDE 136

__global__ __launch_bounds__(256) void gcn_main(const unsigned short* __restrict__ xb,
                                                const int* __restrict__ histg,
                                                const unsigned int* __restrict__ region,
                                                const unsigned short* __restrict__ Wb,
                                                const float* __restrict__ bias,
                                                float* __restrict__ out) {
    __shared__ int cnt[NPR];
    __shared__ unsigned short slot[NPR * CAP];        // 3072 B
    __shared__ unsigned short hs[2 * 16 * FG_STRIDE]; // 8704 B

    int r = blockIdx.x;
    int t = threadIdx.x;
    int wv = t >> 6;
    int lane = t & 63;
    int g = lane >> 4;
    int fl = lane & 15;

    // ---- phase A: bin this range's 313 cells into LDS ----
    if (t < NPR) cnt[t] = 0;
    __syncthreads();
    for (int bb = t; bb < DIST_BLOCKS; bb += 256) {
        int c = histg[r * DIST_BLOCKS + bb];  // coalesced
        if (c > RC) c = RC;
        if (c < 0) c = 0;
        const unsigned int* cell = region + (((size_t)r * DIST_BLOCKS + bb) << 4);
        for (int k = 0; k < c; ++k) {
            unsigned v = cell[k];
            int nd = (v >> 16) & 31;
            int cc = atomicAdd(&cnt[nd], 1);
            if (cc < CAP) slot[nd * CAP + cc] = (unsigned short)(v & 0xFFFFu);
        }
    }
    __syncthreads();
    // pad each node's list to a multiple of 16 with the zero-row index
    if (t < NPR) {
        int c = cnt[t];
        if (c > CAP) c = CAP;
        int cp = (c + 15) & ~15;
        if (cp > CAP) cp = CAP;
        for (int k = c; k < cp; ++k) slot[t * CAP + k] = (unsigned short)ZROW;
        cnt[t] = cp;
    }
    __syncthreads();

    // ---- phase B: gather; wave wv handles nodes wv*8 .. wv*8+7 ----
    for (int k = 0; k < 8; ++k) {
        int nd = wv * 8 + k;
        int cn = cnt[nd];  // multiple of 16, 0..48, wave-uniform
        const unsigned short* bp = slot + nd * CAP;

        uint4 v0, v1, v2, v3, v4, v5, v6, v7, v8, v9, va, vb;
        // burst 0
        if (cn > 0) {
            uint4 w0 = *(const uint4*)(bp);
            uint4 w1 = *(const uint4*)(bp + 8);
            unsigned d0 = (g < 2) ? w0.x : w0.y, d1 = (g < 2) ? w0.z : w0.w;
            unsigned d2 = (g < 2) ? w1.x : w1.y, d3 = (g < 2) ? w1.z : w1.w;
            int sh = (g & 1) * 16;
            v0 = *(const uint4*)(xb + (size_t)((d0 >> sh) & 0xFFFFu) * DIM + fl * 8);
            v1 = *(const uint4*)(xb + (size_t)((d1 >> sh) & 0xFFFFu) * DIM + fl * 8);
            v2 = *(const uint4*)(xb + (size_t)((d2 >> sh) & 0xFFFFu) * DIM + fl * 8);
            v3 = *(const uint4*)(xb + (size_t)((d3 >> sh) & 0xFFFFu) * DIM + fl * 8);
        }
        // burst 1
        if (cn > 16) {
            uint4 w0 = *(const uint4*)(bp + 16);
            uint4 w1 = *(const uint4*)(bp + 24);
            unsigned d0 = (g < 2) ? w0.x : w0.y, d1 = (g < 2) ? w0.z : w0.w;
            unsigned d2 = (g < 2) ? w1.x : w1.y, d3 = (g < 2) ? w1.z : w1.w;
            int sh = (g & 1) * 16;
            v4 = *(const uint4*)(xb + (size_t)((d0 >> sh) & 0xFFFFu) * DIM + fl * 8);
            v5 = *(const uint4*)(xb + (size_t)((d1 >> sh) & 0xFFFFu) * DIM + fl * 8);
            v6 = *(const uint4*)(xb + (size_t)((d2 >> sh) & 0xFFFFu) * DIM + fl * 8);
            v7 = *(const uint4*)(xb + (size_t)((d3 >> sh) & 0xFFFFu) * DIM + fl * 8);
        }
        // burst 2
        if (cn > 32) {
            uint4 w0 = *(const uint4*)(bp + 32);
            uint4 w1 = *(const uint4*)(bp + 40);
            unsigned d0 = (g < 2) ? w0.x : w0.y, d1 = (g < 2) ? w0.z : w0.w;
            unsigned d2 = (g < 2) ? w1.x : w1.y, d3 = (g < 2) ? w1.z : w1.w;
            int sh = (g & 1) * 16;
            v8 = *(const uint4*)(xb + (size_t)((d0 >> sh) & 0xFFFFu) * DIM + fl * 8);
            v9 = *(const uint4*)(xb + (size_t)((d1 >> sh) & 0xFFFFu) * DIM + fl * 8);
            va = *(const uint4*)(xb + (size_t)((d2 >> sh) & 0xFFFFu) * DIM + fl * 8);
            vb = *(const uint4*)(xb + (size_t)((d3 >> sh) & 0xFFFFu) * DIM + fl * 8);
        }

        float acc[8];
#pragma unroll
        for (int j = 0; j < 8; ++j) acc[j] = 0.f;
#define ACCUM(vv)                                                   \
        acc[0] += bflo(vv.x); acc[1] += bfhi(vv.x);                 \
        acc[2] += bflo(vv.y); acc[3] += bfhi(vv.y);                 \
        acc[4] += bflo(vv.z); acc[5] += bfhi(vv.z);                 \
        acc[6] += bflo(vv.w); acc[7] += bfhi(vv.w);
        if (cn > 0)  { ACCUM(v0) ACCUM(v1) ACCUM(v2) ACCUM(v3) }
        if (cn > 16) { ACCUM(v4) ACCUM(v5) ACCUM(v6) ACCUM(v7) }
        if (cn > 32) { ACCUM(v8) ACCUM(v9) ACCUM(va) ACCUM(vb) }
#undef ACCUM

#pragma unroll
        for (int j = 0; j < 8; ++j) {
            acc[j] += __shfl_xor(acc[j], 16);
            acc[j] += __shfl_xor(acc[j], 32);
        }
        if (g == 0) {
            uint4 p;
            p.x = (unsigned)f2bf(acc[0]) | ((unsigned)f2bf(acc[1]) << 16);
            p.y = (unsigned)f2bf(acc[2]) | ((unsigned)f2bf(acc[3]) << 16);
            p.z = (unsigned)f2bf(acc[4]) | ((unsigned)f2bf(acc[5]) << 16);
            p.w = (unsigned)f2bf(acc[6]) | ((unsigned)f2bf(acc[7]) << 16);
            *(uint4*)(hs + (nd >> 4) * 2176 + fl * FG_STRIDE + (nd & 15) * 8) = p;
        }
    }
    __syncthreads();  // tiles are written by two waves each

    // ---- phase C: MFMA; wave w = (tile w&1, j-half w>>1) ----
    int m = fl;
    int quad = g;
    int T = wv & 1;
    const unsigned short* tp = hs + T * 2176;
    bf16x8 a[4];
#pragma unroll
    for (int kb = 0; kb < 4; ++kb) {
        a[kb] = *(const bf16x8*)(tp + (kb * 4 + quad) * FG_STRIDE + m * 8);
    }
    int n0 = r * 32 + T * 16;
#pragma unroll
    for (int j2 = 0; j2 < 4; ++j2) {
        int jt = (wv >> 1) * 4 + j2;
        f32x4 acc4 = (f32x4){0.f, 0.f, 0.f, 0.f};
        const unsigned short* wrow = Wb + (size_t)(jt * 16 + m) * DIM + quad * 8;
#pragma unroll
        for (int kb = 0; kb < 4; ++kb) {
            bf16x8 bf = *(const bf16x8*)(wrow + kb * 32);
            acc4 = __builtin_amdgcn_mfma_f32_16x16x32_bf16(a[kb], bf, acc4, 0, 0, 0);
        }
        float bj = bias[jt * 16 + m];
#pragma unroll
        for (int rr = 0; rr < 4; ++rr) {
            out[(size_t)(n0 + quad * 4 + rr) * DIM + jt * 16 + m] = acc4[rr] + bj;
        }
    }
}

extern "C" void kernel_launch(void* const* d_in, const int* in_sizes, int n_in,
                              void* d_out, int out_size, void* d_ws, size_t ws_size,
                              hipStream_t stream) {
    const float* x = (const float*)d_in[0];
    const int* src = (const int*)d_in[1];
    const int* dst = (const int*)d_in[2];
    const float* W = (const float*)d_in[3];
    const float* b = (const float*)d_in[4];
    float* out = (float*)d_out;

    char* ws = (char*)d_ws;
    int* histg = (int*)ws;                                  // 1250*313*4 = 1,565,000 B
    unsigned int* region = (unsigned int*)(ws + 1568768);   // 1250*313*16*4 = 25,040,000 B
    unsigned short* xb = (unsigned short*)(ws + 26608768);  // 40001 rows = 10,240,256 B
    unsigned short* Wb = (unsigned short*)(ws + 36849152);  // 32,768 B

    prep<<<DIST_BLOCKS + CVX_BLOCKS + 16 + 1, 256, 0, stream>>>(x, W, src, dst,
                                                                histg, region, xb, Wb);

    gcn_main<<<NR, 256, 0, stream>>>(xb, histg, region, Wb, b, out);
}

// Round 12
// 118.841 us; speedup vs baseline: 1.1019x; 1.1019x over previous
//
#include <hip/hip_runtime.h>

// GCN layer: h = segment_sum(x[src], dst); out = h @ W^T + b
// N=40000, E=640000, D=128. Harness compares at bf16 tolerance (0.4625).
// ~57us harness-fixed (256MiB ws poison fill + out/in restores) + ~30us of
// poison-writeback HBM drain overlapping our kernels. r10 = 121.7us.
//
// r12 = r10 structure with phase-A fix; r11's pad-to-16 gather REVERTED
// (+46% gather loads, FETCH 58->67MB, gcn_main 49us - traded traffic for
// mask VALU, bad trade).
//
//  K1 prep: [distribute: 313 blocks x 2048 edges -> LDS hist(1250), write
//     region cells (16-slot, block-local rank) + histg] + x->bf16 + W->bf16
//  K2 gcn_main: 1250 blocks (32-node ranges):
//     A) bin own 313 cells: 4 independent uint4 loads per cell (r10 did up
//        to 16 SERIAL 4B loads - pure latency chain), unrolled guarded insert
//     B) masked MLP-4 gather (wave = 8 nodes, 16 lanes/row, dwordx4)
//     C) mfma_f32_16x16x32_bf16, wave = (tile w&1, j-half w>>1);
//        C/D col=lane&15, row=quad*4+reg (verified r4-r11).

#define NN 40000
#define NE 640000
#define DIM 128
#define CAP 48

#define NR 1250           // 32-node dst ranges; 1250*32 == 40000 exactly
#define NPR 32
#define RC 16             // slots per (range, dist-block) cell; Poisson(1.64)
#define DIST_BLOCKS 313   // x 2048 edges = 641024 >= NE
#define CVX_BLOCKS 5000   // NN*DIM/4/256

typedef __attribute__((ext_vector_type(8))) short bf16x8;
typedef __attribute__((ext_vector_type(4))) float f32x4;

__device__ __forceinline__ unsigned short f2bf(float f) {
    unsigned u = __float_as_uint(f);
    unsigned r = u + 0x7FFFu + ((u >> 16) & 1u);  // RTNE
    return (unsigned short)(r >> 16);
}
__device__ __forceinline__ float bflo(unsigned u) { return __uint_as_float(u << 16); }
__device__ __forceinline__ float bfhi(unsigned u) { return __uint_as_float(u & 0xffff0000u); }

__global__ __launch_bounds__(256) void prep(const float* __restrict__ x,
                                            const float* __restrict__ W,
                                            const int* __restrict__ src,
                                            const int* __restrict__ dst,
                                            int* __restrict__ histg,
                                            unsigned int* __restrict__ region,
                                            unsigned short* __restrict__ xb,
                                            unsigned short* __restrict__ Wb) {
    __shared__ int hist[NR];
    int bid = blockIdx.x;
    int t = threadIdx.x;
    if (bid < DIST_BLOCKS) {
        for (int i = t; i < NR; i += 256) hist[i] = 0;
        __syncthreads();
        int e0 = bid * 2048;
        int dv[8], sv[8], rg8[8], rk8[8];
#pragma unroll
        for (int q = 0; q < 8; ++q) {
            int e = e0 + q * 256 + t;
            if (e < NE) { dv[q] = dst[e]; sv[q] = src[e]; } else dv[q] = -1;
        }
#pragma unroll
        for (int q = 0; q < 8; ++q) {
            if (dv[q] >= 0) { rg8[q] = dv[q] >> 5; rk8[q] = atomicAdd(&hist[rg8[q]], 1); }
        }
#pragma unroll
        for (int q = 0; q < 8; ++q) {
            if (dv[q] >= 0 && (unsigned)rk8[q] < (unsigned)RC) {
                region[(((size_t)rg8[q] * DIST_BLOCKS + bid) << 4) + rk8[q]] =
                    ((unsigned)sv[q] & 0xFFFFu) | (((unsigned)dv[q] & 31u) << 16);
            }
        }
        __syncthreads();  // hist final
        for (int i = t; i < NR; i += 256) histg[i * DIST_BLOCKS + bid] = hist[i];
    } else if (bid < DIST_BLOCKS + CVX_BLOCKS) {
        int i = ((bid - DIST_BLOCKS) * 256 + t) * 4;
        const float4 v = *(const float4*)(x + i);
        ushort4 o;
        o.x = f2bf(v.x); o.y = f2bf(v.y); o.z = f2bf(v.z); o.w = f2bf(v.w);
        *(ushort4*)(xb + i) = o;
    } else {
        int i = ((bid - DIST_BLOCKS - CVX_BLOCKS) * 256 + t) * 4;
        const float4 v = *(const float4*)(W + i);
        ushort4 o;
        o.x = f2bf(v.x); o.y = f2bf(v.y); o.z = f2bf(v.z); o.w = f2bf(v.w);
        *(ushort4*)(Wb + i) = o;
    }
}

// hs: 2 tiles of 16 nodes, fgroup-major: tile T at hs + T*2176 (ushorts);
// fgroup f at +f*136, node k at +k*8 (16B units, conflict-free ds_read_b128).
#define FG_STRIDE 136

__global__ __launch_bounds__(256) void gcn_main(const unsigned short* __restrict__ xb,
                                                const int* __restrict__ histg,
                                                const unsigned int* __restrict__ region,
                                                const unsigned short* __restrict__ Wb,
                                                const float* __restrict__ bias,
                                                float* __restrict__ out) {
    __shared__ int cnt[NPR];
    __shared__ unsigned short slot[NPR * CAP];        // 3072 B
    __shared__ unsigned short hs[2 * 16 * FG_STRIDE]; // 8704 B

    int r = blockIdx.x;
    int t = threadIdx.x;
    int wv = t >> 6;
    int lane = t & 63;
    int g = lane >> 4;
    int fl = lane & 15;

    // ---- phase A: bin this range's 313 cells into LDS ----
    if (t < NPR) cnt[t] = 0;
    __syncthreads();
    for (int bb = t; bb < DIST_BLOCKS; bb += 256) {
        int c = histg[r * DIST_BLOCKS + bb];  // coalesced
        if (c > RC) c = RC;
        if (c < 0) c = 0;
        const uint4* cell = (const uint4*)(region + (((size_t)r * DIST_BLOCKS + bb) << 4));
        // 4 independent 16B loads (r10: up to 16 serial 4B loads here)
        uint4 q0 = cell[0], q1 = cell[1], q2 = cell[2], q3 = cell[3];
        unsigned vals[16] = {q0.x, q0.y, q0.z, q0.w, q1.x, q1.y, q1.z, q1.w,
                             q2.x, q2.y, q2.z, q2.w, q3.x, q3.y, q3.z, q3.w};
#pragma unroll
        for (int k = 0; k < 16; ++k) {  // fully unrolled: compile-time vals[] index
            if (k < c) {
                unsigned v = vals[k];
                int nd = (v >> 16) & 31;
                int cc = atomicAdd(&cnt[nd], 1);
                if (cc < CAP) slot[nd * CAP + cc] = (unsigned short)(v & 0xFFFFu);
            }
        }
    }
    __syncthreads();

    // ---- phase B: masked MLP-4 gather; wave wv handles nodes wv*8..+7 ----
    for (int k = 0; k < 8; ++k) {
        int nd = wv * 8 + k;
        int cn = cnt[nd];
        if (cn > CAP) cn = CAP;
        const unsigned short* bp = slot + nd * CAP;

        float acc[8];
#pragma unroll
        for (int j = 0; j < 8; ++j) acc[j] = 0.f;

        for (int c0 = 0; c0 < cn; c0 += 16) {
            uint4 w0 = *(const uint4*)(bp + c0);       // ds_read, wave-uniform
            uint4 w1 = *(const uint4*)(bp + c0 + 8);
            uint4 v[4];
            float sc[4];
#pragma unroll
            for (int q = 0; q < 4; ++q) {
                unsigned wd = (q == 0) ? ((g < 2) ? w0.x : w0.y)
                            : (q == 1) ? ((g < 2) ? w0.z : w0.w)
                            : (q == 2) ? ((g < 2) ? w1.x : w1.y)
                                       : ((g < 2) ? w1.z : w1.w);
                int sidx = (int)((wd >> ((g & 1) * 16)) & 0xFFFFu);
                int e = c0 + q * 4 + g;
                bool ok = e < cn;
                sc[q] = ok ? 1.f : 0.f;
                sidx = ok ? sidx : 0;  // garbage slots never form an address
                v[q] = *(const uint4*)(xb + (size_t)sidx * DIM + fl * 8);
            }
#pragma unroll
            for (int q = 0; q < 4; ++q) {
                acc[0] = fmaf(sc[q], bflo(v[q].x), acc[0]);
                acc[1] = fmaf(sc[q], bfhi(v[q].x), acc[1]);
                acc[2] = fmaf(sc[q], bflo(v[q].y), acc[2]);
                acc[3] = fmaf(sc[q], bfhi(v[q].y), acc[3]);
                acc[4] = fmaf(sc[q], bflo(v[q].z), acc[4]);
                acc[5] = fmaf(sc[q], bfhi(v[q].z), acc[5]);
                acc[6] = fmaf(sc[q], bflo(v[q].w), acc[6]);
                acc[7] = fmaf(sc[q], bfhi(v[q].w), acc[7]);
            }
        }
#pragma unroll
        for (int j = 0; j < 8; ++j) {
            acc[j] += __shfl_xor(acc[j], 16);
            acc[j] += __shfl_xor(acc[j], 32);
        }
        if (g == 0) {
            uint4 p;
            p.x = (unsigned)f2bf(acc[0]) | ((unsigned)f2bf(acc[1]) << 16);
            p.y = (unsigned)f2bf(acc[2]) | ((unsigned)f2bf(acc[3]) << 16);
            p.z = (unsigned)f2bf(acc[4]) | ((unsigned)f2bf(acc[5]) << 16);
            p.w = (unsigned)f2bf(acc[6]) | ((unsigned)f2bf(acc[7]) << 16);
            *(uint4*)(hs + (nd >> 4) * 2176 + fl * FG_STRIDE + (nd & 15) * 8) = p;
        }
    }
    __syncthreads();  // tiles are written by two waves each

    // ---- phase C: MFMA; wave w = (tile w&1, j-half w>>1) ----
    int m = fl;
    int quad = g;
    int T = wv & 1;
    const unsigned short* tp = hs + T * 2176;
    bf16x8 a[4];
#pragma unroll
    for (int kb = 0; kb < 4; ++kb) {
        a[kb] = *(const bf16x8*)(tp + (kb * 4 + quad) * FG_STRIDE + m * 8);
    }
    int n0 = r * 32 + T * 16;
#pragma unroll
    for (int j2 = 0; j2 < 4; ++j2) {
        int jt = (wv >> 1) * 4 + j2;
        f32x4 acc4 = (f32x4){0.f, 0.f, 0.f, 0.f};
        const unsigned short* wrow = Wb + (size_t)(jt * 16 + m) * DIM + quad * 8;
#pragma unroll
        for (int kb = 0; kb < 4; ++kb) {
            bf16x8 bf = *(const bf16x8*)(wrow + kb * 32);
            acc4 = __builtin_amdgcn_mfma_f32_16x16x32_bf16(a[kb], bf, acc4, 0, 0, 0);
        }
        float bj = bias[jt * 16 + m];
#pragma unroll
        for (int rr = 0; rr < 4; ++rr) {
            out[(size_t)(n0 + quad * 4 + rr) * DIM + jt * 16 + m] = acc4[rr] + bj;
        }
    }
}

extern "C" void kernel_launch(void* const* d_in, const int* in_sizes, int n_in,
                              void* d_out, int out_size, void* d_ws, size_t ws_size,
                              hipStream_t stream) {
    const float* x = (const float*)d_in[0];
    const int* src = (const int*)d_in[1];
    const int* dst = (const int*)d_in[2];
    const float* W = (const float*)d_in[3];
    const float* b = (const float*)d_in[4];
    float* out = (float*)d_out;

    char* ws = (char*)d_ws;
    int* histg = (int*)ws;                                  // 1250*313*4 = 1,565,000 B
    unsigned int* region = (unsigned int*)(ws + 1568768);   // 1250*313*16*4 = 25,040,000 B
    unsigned short* xb = (unsigned short*)(ws + 26608768);  // 10,240,000 B
    unsigned short* Wb = (unsigned short*)(ws + 36848768);  // 32,768 B

    prep<<<DIST_BLOCKS + CVX_BLOCKS + 16, 256, 0, stream>>>(x, W, src, dst,
                                                            histg, region, xb, Wb);

    gcn_main<<<NR, 256, 0, stream>>>(xb, histg, region, Wb, b, out);
}